// Round 1
// baseline (5133.261 us; speedup 1.0000x reference)
//
#include <hip/hip_runtime.h>
#include <math.h>

#define BATCH   512
#define N       128
#define DDIM    1024
#define NITER   30
#define SIGMA_C 0.1f
#define EPS_C   1e-6f
#define NB      16
#define MPAD    132   // row stride: 132*4B = 528B, 16B-aligned rows

// ---------------- Kernel A: Q = 2*(X X^T + eps I) ----------------
__global__ __launch_bounds__(256) void gram_kernel(const float* __restrict__ X,
                                                   float* __restrict__ Q) {
    const int b = blockIdx.x;
    const float* Xb = X + (size_t)b * N * DDIM;
    float* Qb = Q + (size_t)b * N * N;

    __shared__ float Xs[16][MPAD];   // k-chunk, transposed: Xs[kk][i]
    const int t  = threadIdx.x;
    const int tx = t & 15, ty = t >> 4;
    const int li = t >> 1;
    const int lk = (t & 1) * 8;

    float acc[8][8];
#pragma unroll
    for (int u = 0; u < 8; ++u)
#pragma unroll
        for (int v = 0; v < 8; ++v) acc[u][v] = 0.0f;

    for (int k0 = 0; k0 < DDIM; k0 += 16) {
        const float4 p0 = *(const float4*)(Xb + (size_t)li * DDIM + k0 + lk);
        const float4 p1 = *(const float4*)(Xb + (size_t)li * DDIM + k0 + lk + 4);
        __syncthreads();
        Xs[lk + 0][li] = p0.x; Xs[lk + 1][li] = p0.y;
        Xs[lk + 2][li] = p0.z; Xs[lk + 3][li] = p0.w;
        Xs[lk + 4][li] = p1.x; Xs[lk + 5][li] = p1.y;
        Xs[lk + 6][li] = p1.z; Xs[lk + 7][li] = p1.w;
        __syncthreads();
#pragma unroll
        for (int kk = 0; kk < 16; ++kk) {
            float4 A0 = *(const float4*)&Xs[kk][ty * 8];
            float4 A1 = *(const float4*)&Xs[kk][ty * 8 + 4];
            float4 C0 = *(const float4*)&Xs[kk][tx * 8];
            float4 C1 = *(const float4*)&Xs[kk][tx * 8 + 4];
            float a[8] = {A0.x, A0.y, A0.z, A0.w, A1.x, A1.y, A1.z, A1.w};
            float c[8] = {C0.x, C0.y, C0.z, C0.w, C1.x, C1.y, C1.z, C1.w};
#pragma unroll
            for (int u = 0; u < 8; ++u)
#pragma unroll
                for (int v = 0; v < 8; ++v) acc[u][v] += a[u] * c[v];
        }
    }
#pragma unroll
    for (int u = 0; u < 8; ++u) {
        const int i = ty * 8 + u;
#pragma unroll
        for (int v = 0; v < 8; ++v) {
            const int k = tx * 8 + v;
            acc[u][v] = 2.0f * acc[u][v] + ((i == k) ? 2.0f * EPS_C : 0.0f);
        }
        float4 o0, o1;
        o0.x = acc[u][0]; o0.y = acc[u][1]; o0.z = acc[u][2]; o0.w = acc[u][3];
        o1.x = acc[u][4]; o1.y = acc[u][5]; o1.z = acc[u][6]; o1.w = acc[u][7];
        *(float4*)(Qb + (size_t)i * N + tx * 8)     = o0;
        *(float4*)(Qb + (size_t)i * N + tx * 8 + 4) = o1;
    }
}

// ---------------- Kernel B: primal-dual IPM, one block per batch ----------------
__global__ __launch_bounds__(256) void ipm_kernel(const float* __restrict__ Q,
                                                  float* __restrict__ alphas) {
    const int b = blockIdx.x;
    const float* Qb = Q + (size_t)b * N * N;

    __shared__ float M[N][MPAD];                 // 67584 B
    __shared__ float av[N], lamv[N], Pp[N], v0[N], v1[N], qa[N], dinv[N];
    __shared__ float part[256];
    __shared__ float scal[8];  // 0:nu 1:mu 2:r_pri 3:dnu 4:t_step

    const int t = threadIdx.x;
    const int lane = t & 63;
    const int wave = t >> 6;

    if (t < N) {
        av[t]   = 1.0f / (float)N;
        lamv[t] = 1.0f;
        Pp[t]   = -0.5f * Qb[t * N + t];         // p = -diag(K)
    }
    if (t == 0) scal[0] = 0.0f;                  // nu
    __syncthreads();

    for (int iter = 0; iter < NITER; ++iter) {
        // ---- reload Q into M (coalesced float4) ----
#pragma unroll
        for (int p = 0; p < 16; ++p) {
            const int f = t + p * 256;           // float4 index, < 4096
            const int row = f >> 5;
            const int col = (f & 31) << 2;
            *(float4*)&M[row][col] = *(const float4*)(Qb + row * N + col);
        }
        __syncthreads();
        // ---- qa = Q @ a (two threads per row) ----
        {
            const int i = t >> 1, h = t & 1;
            const float* Mr = &M[i][h * 64];
            const float* ar = &av[h * 64];
            float s = 0.0f;
#pragma unroll
            for (int k = 0; k < 64; k += 4) {
                float4 m4 = *(const float4*)(Mr + k);
                float4 a4 = *(const float4*)(ar + k);
                s += m4.x * a4.x + m4.y * a4.y + m4.z * a4.z + m4.w * a4.w;
            }
            part[t] = s;
        }
        __syncthreads();
        if (t < N) qa[t] = part[2 * t] + part[2 * t + 1];
        if (wave == 0) {                         // r_pri, mu
            float sa  = av[lane] + av[lane + 64];
            float sal = av[lane] * lamv[lane] + av[lane + 64] * lamv[lane + 64];
#pragma unroll
            for (int o = 32; o; o >>= 1) {
                sa  += __shfl_xor(sa, o);
                sal += __shfl_xor(sal, o);
            }
            if (lane == 0) { scal[2] = sa - 1.0f; scal[1] = sal / (float)N; }
        }
        __syncthreads();
        const float mu = scal[1];
        const float nu = scal[0];
        // ---- rhs build + diagonal shift ----
        if (t < N) {
            const float ai = av[t], li = lamv[t];
            const float rd = qa[t] + Pp[t] - li + nu;
            v0[t] = -(rd + li - SIGMA_C * mu / ai);   // -(r_dual + r_cent/a)
            v1[t] = 1.0f;
            M[t][t] += li / ai;
        }
        __syncthreads();

        // ---- blocked Cholesky (lower), NB=16 ----
        for (int jb = 0; jb < N / NB; ++jb) {
            const int j0 = jb * NB;
            // (a) diagonal block factor on wave 0 (shfl-based, no barriers)
            if (wave == 0) {
                for (int c = 0; c < NB; ++c) {
                    const int j = j0 + c;
                    const float djj = M[j][j];
                    const float rL = sqrtf(djj);
                    const float ri = 1.0f / rL;
                    float tv = 0.0f;
                    if (lane > c && lane < NB) tv = M[j0 + lane][j] * ri;
                    if (lane == c) { M[j][j] = rL; dinv[j] = ri; }
                    if (lane > c && lane < NB) M[j0 + lane][j] = tv;
                    for (int k = c + 1; k < NB; ++k) {
                        const float tk = __shfl(tv, k);
                        if (lane >= k && lane < NB) M[j0 + lane][j0 + k] -= tv * tk;
                    }
                }
            }
            __syncthreads();
            const int rem = N - j0 - NB;
            // (b) panel solve: one row per thread, L21 = M21 * Ld^{-T}
            if (t < rem) {
                const int i = j0 + NB + t;
                float w[NB];
#pragma unroll
                for (int c = 0; c < NB; ++c) w[c] = M[i][j0 + c];
#pragma unroll
                for (int c = 0; c < NB; ++c) {
                    float s = w[c];
#pragma unroll
                    for (int m = 0; m < c; ++m) s -= w[m] * M[j0 + c][j0 + m];
                    w[c] = s * dinv[j0 + c];
                }
#pragma unroll
                for (int c = 0; c < NB; ++c) M[i][j0 + c] = w[c];
            }
            __syncthreads();
            // (c) trailing SYRK: M22 -= L21*L21^T, 64x64 tiles, 4x4 regs/thread
            if (rem > 0) {
                const int g = (rem + 63) >> 6;
                const int ty = t >> 4, tx = t & 15;
                for (int bi = 0; bi < g; ++bi) {
                    for (int bk = 0; bk <= bi; ++bk) {
                        const int i0 = j0 + NB + bi * 64 + ty * 4;
                        const int k0 = j0 + NB + bk * 64 + tx * 4;
                        if (i0 < N && k0 < N && (bi != bk || k0 <= i0 + 3)) {
                            float acc4[4][4];
#pragma unroll
                            for (int u = 0; u < 4; ++u) {
                                const float4 r = *(const float4*)&M[i0 + u][k0];
                                acc4[u][0] = r.x; acc4[u][1] = r.y;
                                acc4[u][2] = r.z; acc4[u][3] = r.w;
                            }
#pragma unroll
                            for (int m0 = 0; m0 < NB; m0 += 4) {
                                float4 A[4], Bv[4];
#pragma unroll
                                for (int u = 0; u < 4; ++u)
                                    A[u] = *(const float4*)&M[i0 + u][j0 + m0];
#pragma unroll
                                for (int v = 0; v < 4; ++v)
                                    Bv[v] = *(const float4*)&M[k0 + v][j0 + m0];
#pragma unroll
                                for (int u = 0; u < 4; ++u)
#pragma unroll
                                    for (int v = 0; v < 4; ++v)
                                        acc4[u][v] -= A[u].x * Bv[v].x + A[u].y * Bv[v].y
                                                    + A[u].z * Bv[v].z + A[u].w * Bv[v].w;
                            }
#pragma unroll
                            for (int u = 0; u < 4; ++u) {
                                float4 r;
                                r.x = acc4[u][0]; r.y = acc4[u][1];
                                r.z = acc4[u][2]; r.w = acc4[u][3];
                                *(float4*)&M[i0 + u][k0] = r;
                            }
                        }
                    }
                }
            }
            __syncthreads();
        }

        // ---- triangular solves (both RHS) entirely on wave 0 ----
        if (wave == 0) {
            const int r0 = lane, r1 = lane + 64;
            float b00 = v0[r0], b01 = v0[r1];
            float b10 = v1[r0], b11 = v1[r1];
            for (int c = 0; c < N; ++c) {        // L y = b
                const float di = dinv[c];
                const float s0 = (c < 64) ? b00 : b01;
                const float s1 = (c < 64) ? b10 : b11;
                const float y0 = __shfl(s0, c & 63) * di;
                const float y1 = __shfl(s1, c & 63) * di;
                const float L0 = M[r0][c];
                const float L1 = M[r1][c];
                if (r0 > c)       { b00 -= L0 * y0; b10 -= L0 * y1; }
                else if (r0 == c) { b00 = y0;       b10 = y1; }
                if (r1 > c)       { b01 -= L1 * y0; b11 -= L1 * y1; }
                else if (r1 == c) { b01 = y0;       b11 = y1; }
            }
            for (int c = N - 1; c >= 0; --c) {   // L^T x = y
                const float di = dinv[c];
                const float s0 = (c < 64) ? b00 : b01;
                const float s1 = (c < 64) ? b10 : b11;
                const float x0 = __shfl(s0, c & 63) * di;
                const float x1 = __shfl(s1, c & 63) * di;
                const float L0 = M[c][r0];
                const float L1 = M[c][r1];
                if (r0 < c)       { b00 -= L0 * x0; b10 -= L0 * x1; }
                else if (r0 == c) { b00 = x0;       b10 = x1; }
                if (r1 < c)       { b01 -= L1 * x0; b11 -= L1 * x1; }
                else if (r1 == c) { b01 = x0;       b11 = x1; }
            }
            v0[r0] = b00; v0[r1] = b01;
            v1[r0] = b10; v1[r1] = b11;
            float s0 = b00 + b01;
            float s1 = b10 + b11;
#pragma unroll
            for (int o = 32; o; o >>= 1) {
                s0 += __shfl_xor(s0, o);
                s1 += __shfl_xor(s1, o);
            }
            if (lane == 0) scal[3] = (s0 + scal[2]) / s1;   // dnu
        }
        __syncthreads();
        // ---- step size (wave 0) ----
        if (wave == 0) {
            const float dnu = scal[3];
            float r = 3.4e38f;
            const int l0 = lane, l1 = lane + 64;
            const float a0 = av[l0], a1 = av[l1];
            const float lm0 = lamv[l0], lm1 = lamv[l1];
            const float da0 = v0[l0] - dnu * v1[l0];
            const float da1 = v0[l1] - dnu * v1[l1];
            const float dl0 = -lm0 + SIGMA_C * mu / a0 - lm0 * da0 / a0;
            const float dl1 = -lm1 + SIGMA_C * mu / a1 - lm1 * da1 / a1;
            if (da0 < 0.0f) r = fminf(r, -a0 / da0);
            if (da1 < 0.0f) r = fminf(r, -a1 / da1);
            if (dl0 < 0.0f) r = fminf(r, -lm0 / dl0);
            if (dl1 < 0.0f) r = fminf(r, -lm1 / dl1);
#pragma unroll
            for (int o = 32; o; o >>= 1) r = fminf(r, __shfl_xor(r, o));
            if (lane == 0) scal[4] = fminf(1.0f, 0.99f * r);
        }
        __syncthreads();
        // ---- update ----
        {
            const float ts  = scal[4];
            const float dnu = scal[3];
            if (t < N) {
                const float ai = av[t], li = lamv[t];
                const float dai = v0[t] - dnu * v1[t];
                const float dli = -li + SIGMA_C * mu / ai - li * dai / ai;
                av[t]   = ai + ts * dai;
                lamv[t] = li + ts * dli;
            }
            if (t == 0) scal[0] = nu + ts * dnu;
        }
        __syncthreads();
    }

    if (t < N) alphas[(size_t)b * N + t] = av[t];
}

// ---------------- Kernel C: centers = alpha^T X ----------------
__global__ __launch_bounds__(256) void centers_kernel(const float* __restrict__ X,
                                                      const float* __restrict__ alphas,
                                                      float* __restrict__ out) {
    const int b = blockIdx.x;
    __shared__ float al[N];
    const int t = threadIdx.x;
    if (t < N) al[t] = alphas[(size_t)b * N + t];
    __syncthreads();
    const float* Xb = X + (size_t)b * N * DDIM;
    float acc0 = 0.0f, acc1 = 0.0f, acc2 = 0.0f, acc3 = 0.0f;
    for (int s = 0; s < N; ++s) {
        const float a = al[s];
        const float* row = Xb + (size_t)s * DDIM + t;
        acc0 += a * row[0];
        acc1 += a * row[256];
        acc2 += a * row[512];
        acc3 += a * row[768];
    }
    float* ob = out + (size_t)b * DDIM + t;
    ob[0]   = acc0;
    ob[256] = acc1;
    ob[512] = acc2;
    ob[768] = acc3;
}

extern "C" void kernel_launch(void* const* d_in, const int* in_sizes, int n_in,
                              void* d_out, int out_size, void* d_ws, size_t ws_size,
                              hipStream_t stream) {
    (void)in_sizes; (void)n_in; (void)out_size; (void)ws_size;
    const float* X = (const float*)d_in[0];
    float* out = (float*)d_out;
    float* Q = (float*)d_ws;                                  // 512*128*128 f32 = 32 MB
    float* alphas = Q + (size_t)BATCH * N * N;                // + 256 KB
    gram_kernel<<<dim3(BATCH), dim3(256), 0, stream>>>(X, Q);
    ipm_kernel<<<dim3(BATCH), dim3(256), 0, stream>>>(Q, alphas);
    centers_kernel<<<dim3(BATCH), dim3(256), 0, stream>>>(X, alphas, out);
}

// Round 2
// 4067.722 us; speedup vs baseline: 1.2619x; 1.2619x over previous
//
#include <hip/hip_runtime.h>
#include <math.h>

#define BATCH   512
#define N       128
#define DDIM    1024
#define NITER   30
#define SIGMA_C 0.1f
#define EPS_C   1e-6f
#define NB      16
#define MPAD    132   // gram kernel staging stride

// Swizzled LDS index for the 130x128 augmented matrix: stride 128 floats,
// float4-chunk XOR swizzle on (row & 7) -> column accesses spread over 8 bank-quads.
__device__ __forceinline__ int midx(int r, int c) {
    return (r << 7) + ((((c) >> 2) ^ (r & 7)) << 2) + (c & 3);
}

// ---------------- Kernel A: Q = 2*(X X^T + eps I) ----------------
__global__ __launch_bounds__(256) void gram_kernel(const float* __restrict__ X,
                                                   float* __restrict__ Q) {
    const int b = blockIdx.x;
    const float* Xb = X + (size_t)b * N * DDIM;
    float* Qb = Q + (size_t)b * N * N;

    __shared__ float Xs[16][MPAD];   // k-chunk, transposed: Xs[kk][i]
    const int t  = threadIdx.x;
    const int tx = t & 15, ty = t >> 4;
    const int li = t >> 1;
    const int lk = (t & 1) * 8;

    float acc[8][8];
#pragma unroll
    for (int u = 0; u < 8; ++u)
#pragma unroll
        for (int v = 0; v < 8; ++v) acc[u][v] = 0.0f;

    for (int k0 = 0; k0 < DDIM; k0 += 16) {
        const float4 p0 = *(const float4*)(Xb + (size_t)li * DDIM + k0 + lk);
        const float4 p1 = *(const float4*)(Xb + (size_t)li * DDIM + k0 + lk + 4);
        __syncthreads();
        Xs[lk + 0][li] = p0.x; Xs[lk + 1][li] = p0.y;
        Xs[lk + 2][li] = p0.z; Xs[lk + 3][li] = p0.w;
        Xs[lk + 4][li] = p1.x; Xs[lk + 5][li] = p1.y;
        Xs[lk + 6][li] = p1.z; Xs[lk + 7][li] = p1.w;
        __syncthreads();
#pragma unroll
        for (int kk = 0; kk < 16; ++kk) {
            float4 A0 = *(const float4*)&Xs[kk][ty * 8];
            float4 A1 = *(const float4*)&Xs[kk][ty * 8 + 4];
            float4 C0 = *(const float4*)&Xs[kk][tx * 8];
            float4 C1 = *(const float4*)&Xs[kk][tx * 8 + 4];
            float a[8] = {A0.x, A0.y, A0.z, A0.w, A1.x, A1.y, A1.z, A1.w};
            float c[8] = {C0.x, C0.y, C0.z, C0.w, C1.x, C1.y, C1.z, C1.w};
#pragma unroll
            for (int u = 0; u < 8; ++u)
#pragma unroll
                for (int v = 0; v < 8; ++v) acc[u][v] += a[u] * c[v];
        }
    }
#pragma unroll
    for (int u = 0; u < 8; ++u) {
        const int i = ty * 8 + u;
#pragma unroll
        for (int v = 0; v < 8; ++v) {
            const int k = tx * 8 + v;
            acc[u][v] = 2.0f * acc[u][v] + ((i == k) ? 2.0f * EPS_C : 0.0f);
        }
        float4 o0, o1;
        o0.x = acc[u][0]; o0.y = acc[u][1]; o0.z = acc[u][2]; o0.w = acc[u][3];
        o1.x = acc[u][4]; o1.y = acc[u][5]; o1.z = acc[u][6]; o1.w = acc[u][7];
        *(float4*)(Qb + (size_t)i * N + tx * 8)     = o0;
        *(float4*)(Qb + (size_t)i * N + tx * 8 + 4) = o1;
    }
}

// ---------------- Kernel B: primal-dual IPM, one block per batch ----------------
// Augmented 130x128 matrix in swizzled LDS: rows 0..127 = M, rows 128/129 = the
// two RHS vectors. Panel-solve + SYRK on the RHS rows compute y = L^-1 b as a
// side effect of the factorization (forward substitution fused, zero extra chain).
__global__ __launch_bounds__(256) void ipm_kernel(const float* __restrict__ Q,
                                                  float* __restrict__ alphas) {
    const int b = blockIdx.x;
    const float* Qb = Q + (size_t)b * N * N;

    __shared__ __align__(16) float Mlds[(N + 2) * N];     // 66560 B
    __shared__ __align__(16) float av[N], lamv[N], Pp[N], v0[N], v1[N], qa[N], dinv[N];
    __shared__ float part[256];
    __shared__ float scal[8];  // 0:nu 1:mu 2:r_pri 3:dnu 4:t_step

    const int t = threadIdx.x;
    const int lane = t & 63;
    const int wave = t >> 6;

    if (t < N) {
        av[t]   = 1.0f / (float)N;
        lamv[t] = 1.0f;
        Pp[t]   = -0.5f * Qb[t * N + t];         // p = -diag(K)
    }
    if (t == 0) scal[0] = 0.0f;                  // nu
    __syncthreads();

    for (int iter = 0; iter < NITER; ++iter) {
        // ---- reload Q into M (coalesced float4, swizzled LDS write) ----
#pragma unroll
        for (int p = 0; p < 16; ++p) {
            const int f = t + (p << 8);          // float4 index, < 4096
            const int row = f >> 5;
            const int col = (f & 31) << 2;
            *(float4*)&Mlds[midx(row, col)] = *(const float4*)(Qb + (size_t)row * N + col);
        }
        __syncthreads();
        // ---- qa = Q @ a (two threads per row) ----
        {
            const int i = t >> 1, h = t & 1;
            float s = 0.0f;
#pragma unroll
            for (int k = 0; k < 64; k += 4) {
                const float4 m4 = *(const float4*)&Mlds[midx(i, h * 64 + k)];
                const float4 a4 = *(const float4*)&av[h * 64 + k];
                s += m4.x * a4.x + m4.y * a4.y + m4.z * a4.z + m4.w * a4.w;
            }
            part[t] = s;
        }
        __syncthreads();
        if (t < N) qa[t] = part[2 * t] + part[2 * t + 1];
        if (wave == 0) {                         // r_pri, mu
            float sa  = av[lane] + av[lane + 64];
            float sal = av[lane] * lamv[lane] + av[lane + 64] * lamv[lane + 64];
#pragma unroll
            for (int o = 32; o; o >>= 1) {
                sa  += __shfl_xor(sa, o);
                sal += __shfl_xor(sal, o);
            }
            if (lane == 0) { scal[2] = sa - 1.0f; scal[1] = sal / (float)N; }
        }
        __syncthreads();
        const float mu = scal[1];
        const float nu = scal[0];
        // ---- rhs rows + diagonal shift ----
        if (t < N) {
            const float ai = av[t], li = lamv[t];
            const float rd = qa[t] + Pp[t] - li + nu;
            Mlds[midx(N, t)]     = -(rd + li - SIGMA_C * mu / ai);  // rhs0
            Mlds[midx(N + 1, t)] = 1.0f;                            // rhs1
            Mlds[midx(t, t)] += li / ai;
        }
        __syncthreads();

        // ---- blocked Cholesky (lower), NB=16, RHS rows ride along ----
        for (int jb = 0; jb < N / NB; ++jb) {
            const int j0 = jb * NB;
            // (a) diagonal block factor: register-resident on wave 0, shfl-only chain
            if (wave == 0) {
                const int r = lane;
                float row[NB];
                if (r < NB) {
#pragma unroll
                    for (int c = 0; c < NB; ++c) row[c] = Mlds[midx(j0 + r, j0 + c)];
                } else {
#pragma unroll
                    for (int c = 0; c < NB; ++c) row[c] = 1.0f;
                }
                float myri = 0.0f;
#pragma unroll
                for (int c = 0; c < NB; ++c) {
                    const float d  = __shfl(row[c], c);   // current pivot
                    const float ri = rsqrtf(d);
                    const float rl = d * ri;
                    if (r == c) { row[c] = rl; myri = ri; }
                    const float lv = (r > c && r < NB) ? row[c] * ri : 0.0f;
                    if (r > c && r < NB) row[c] = lv;
#pragma unroll
                    for (int k = c + 1; k < NB; ++k) {
                        const float lk = __shfl(lv, k);   // L[k][c]
                        row[k] -= lv * lk;                // no-op when lv==0
                    }
                }
                if (r < NB) {
#pragma unroll
                    for (int c = 0; c < NB; ++c) Mlds[midx(j0 + r, j0 + c)] = row[c];
                    dinv[j0 + r] = myri;
                }
            }
            __syncthreads();
            // (b) panel solve: rows j0+NB..129 (incl. RHS rows), one per thread
            const int cnt = (N + 2) - (j0 + NB);
            if (t < cnt) {
                const int i = j0 + NB + t;
                float w[NB];
#pragma unroll
                for (int c = 0; c < NB; ++c) w[c] = Mlds[midx(i, j0 + c)];
#pragma unroll
                for (int c = 0; c < NB; ++c) {
                    float s = w[c];
#pragma unroll
                    for (int m = 0; m < c; ++m) s -= w[m] * Mlds[midx(j0 + c, j0 + m)];
                    w[c] = s * dinv[j0 + c];
                }
#pragma unroll
                for (int c = 0; c < NB; ++c) Mlds[midx(i, j0 + c)] = w[c];
            }
            __syncthreads();
            // (c) trailing update: A22 -= L21 L21^T (RHS rows get forward-sub updates)
            const int ib0 = j0 + NB;
            const int RR = (N + 2) - ib0;     // rows incl. RHS
            const int KK = N - ib0;           // matrix cols only
            if (KK > 0) {
                const int nbi = (RR + 63) >> 6, nbk = (KK + 63) >> 6;
                const int ty = t >> 4, tx = t & 15;
                for (int bi = 0; bi < nbi; ++bi) {
                    const int i0t = ib0 + bi * 64;
                    for (int bk = 0; bk < nbk; ++bk) {
                        const int k0t = ib0 + bk * 64;
                        if (k0t > i0t + 63) continue;   // strictly-above tile
                        int irow[4], kcol[4];
#pragma unroll
                        for (int u = 0; u < 4; ++u) irow[u] = i0t + ty + 16 * u;
#pragma unroll
                        for (int v = 0; v < 4; ++v) kcol[v] = k0t + tx + 16 * v;
                        float acc[4][4];
#pragma unroll
                        for (int u = 0; u < 4; ++u) {
                            const int iu = irow[u] < N + 2 ? irow[u] : N + 1;
#pragma unroll
                            for (int v = 0; v < 4; ++v) {
                                const int kv = kcol[v] < N ? kcol[v] : N - 1;
                                acc[u][v] = Mlds[midx(iu, kv)];
                            }
                        }
#pragma unroll
                        for (int m0 = 0; m0 < NB; m0 += 4) {
                            float4 A[4], B[4];
#pragma unroll
                            for (int u = 0; u < 4; ++u) {
                                const int iu = irow[u] < N + 2 ? irow[u] : N + 1;
                                A[u] = *(const float4*)&Mlds[midx(iu, j0 + m0)];
                            }
#pragma unroll
                            for (int v = 0; v < 4; ++v) {
                                const int kv = kcol[v] < N ? kcol[v] : N - 1;
                                B[v] = *(const float4*)&Mlds[midx(kv, j0 + m0)];
                            }
#pragma unroll
                            for (int u = 0; u < 4; ++u)
#pragma unroll
                                for (int v = 0; v < 4; ++v)
                                    acc[u][v] -= A[u].x * B[v].x + A[u].y * B[v].y
                                               + A[u].z * B[v].z + A[u].w * B[v].w;
                        }
#pragma unroll
                        for (int u = 0; u < 4; ++u)
#pragma unroll
                            for (int v = 0; v < 4; ++v)
                                if (irow[u] < N + 2 && kcol[v] < N)
                                    Mlds[midx(irow[u], kcol[v])] = acc[u][v];
                    }
                }
            }
            __syncthreads();
        }

        // ---- backward solve (L^T x = y) + dnu + step size, all on wave 0 ----
        if (wave == 0) {
            const int r0 = lane, r1 = lane + 64;
            float b00 = Mlds[midx(N, r0)],     b01 = Mlds[midx(N, r1)];
            float b10 = Mlds[midx(N + 1, r0)], b11 = Mlds[midx(N + 1, r1)];
            for (int c = N - 1; c >= 0; --c) {
                const float di = dinv[c];
                const float s0 = (c < 64) ? b00 : b01;
                const float s1 = (c < 64) ? b10 : b11;
                const float x0 = __shfl(s0, c & 63) * di;
                const float x1 = __shfl(s1, c & 63) * di;
                const float L0 = Mlds[midx(c, r0)];   // L[c][r], row access
                const float L1 = Mlds[midx(c, r1)];
                if (r0 < c)       { b00 -= L0 * x0; b10 -= L0 * x1; }
                else if (r0 == c) { b00 = x0;       b10 = x1; }
                if (r1 < c)       { b01 -= L1 * x0; b11 -= L1 * x1; }
                else if (r1 == c) { b01 = x0;       b11 = x1; }
            }
            v0[r0] = b00; v0[r1] = b01;
            v1[r0] = b10; v1[r1] = b11;
            float s0 = b00 + b01;
            float s1 = b10 + b11;
#pragma unroll
            for (int o = 32; o; o >>= 1) {
                s0 += __shfl_xor(s0, o);
                s1 += __shfl_xor(s1, o);
            }
            const float dnu = (s0 + scal[2]) / s1;   // full sums on all lanes
            // step size
            float r = 3.4e38f;
            const float a0 = av[r0], a1 = av[r1];
            const float lm0 = lamv[r0], lm1 = lamv[r1];
            const float da0 = b00 - dnu * b10;
            const float da1 = b01 - dnu * b11;
            const float dl0 = -lm0 + SIGMA_C * mu / a0 - lm0 * da0 / a0;
            const float dl1 = -lm1 + SIGMA_C * mu / a1 - lm1 * da1 / a1;
            if (da0 < 0.0f) r = fminf(r, -a0 / da0);
            if (da1 < 0.0f) r = fminf(r, -a1 / da1);
            if (dl0 < 0.0f) r = fminf(r, -lm0 / dl0);
            if (dl1 < 0.0f) r = fminf(r, -lm1 / dl1);
#pragma unroll
            for (int o = 32; o; o >>= 1) r = fminf(r, __shfl_xor(r, o));
            if (lane == 0) { scal[3] = dnu; scal[4] = fminf(1.0f, 0.99f * r); }
        }
        __syncthreads();
        // ---- update ----
        {
            const float ts  = scal[4];
            const float dnu = scal[3];
            if (t < N) {
                const float ai = av[t], li = lamv[t];
                const float dai = v0[t] - dnu * v1[t];
                const float dli = -li + SIGMA_C * mu / ai - li * dai / ai;
                av[t]   = ai + ts * dai;
                lamv[t] = li + ts * dli;
            }
            if (t == 0) scal[0] = nu + ts * dnu;
        }
        __syncthreads();
    }

    if (t < N) alphas[(size_t)b * N + t] = av[t];
}

// ---------------- Kernel C: centers = alpha^T X ----------------
__global__ __launch_bounds__(256) void centers_kernel(const float* __restrict__ X,
                                                      const float* __restrict__ alphas,
                                                      float* __restrict__ out) {
    const int b = blockIdx.x;
    __shared__ float al[N];
    const int t = threadIdx.x;
    if (t < N) al[t] = alphas[(size_t)b * N + t];
    __syncthreads();
    const float* Xb = X + (size_t)b * N * DDIM;
    float acc0 = 0.0f, acc1 = 0.0f, acc2 = 0.0f, acc3 = 0.0f;
    for (int s = 0; s < N; ++s) {
        const float a = al[s];
        const float* row = Xb + (size_t)s * DDIM + t;
        acc0 += a * row[0];
        acc1 += a * row[256];
        acc2 += a * row[512];
        acc3 += a * row[768];
    }
    float* ob = out + (size_t)b * DDIM + t;
    ob[0]   = acc0;
    ob[256] = acc1;
    ob[512] = acc2;
    ob[768] = acc3;
}

extern "C" void kernel_launch(void* const* d_in, const int* in_sizes, int n_in,
                              void* d_out, int out_size, void* d_ws, size_t ws_size,
                              hipStream_t stream) {
    (void)in_sizes; (void)n_in; (void)out_size; (void)ws_size;
    const float* X = (const float*)d_in[0];
    float* out = (float*)d_out;
    float* Q = (float*)d_ws;                                  // 512*128*128 f32 = 32 MB
    float* alphas = Q + (size_t)BATCH * N * N;                // + 256 KB
    gram_kernel<<<dim3(BATCH), dim3(256), 0, stream>>>(X, Q);
    ipm_kernel<<<dim3(BATCH), dim3(256), 0, stream>>>(Q, alphas);
    centers_kernel<<<dim3(BATCH), dim3(256), 0, stream>>>(X, alphas, out);
}